// Round 1
// baseline (144.791 us; speedup 1.0000x reference)
//
#include <hip/hip_runtime.h>
#include <hip/hip_bf16.h>
#include <math.h>

#define L_LEN 250
#define D_DIM 128
#define C_DIM 32
#define DIN   160
#define NV    16
#define T_LEN 62400
#define LT    16

// ---------------- Kernel 1: z-mean + MLP -> per-batch params ----------------
// P layout per batch (40 floats): [0]=depth, [1]=coef=1/(norm+1e-6),
// [2..17]=mask[v], [18..33]=pan[v]
__global__ void params_kernel(const float* __restrict__ z, const float* __restrict__ cond,
                              const float* __restrict__ W1, const float* __restrict__ b1,
                              const float* __restrict__ W2, const float* __restrict__ b2,
                              const float* __restrict__ W3, const float* __restrict__ b3,
                              const float* __restrict__ W4, const float* __restrict__ b4,
                              float* __restrict__ P) {
    int b = blockIdx.x;
    int tid = threadIdx.x;
    __shared__ float xb[DIN];
    __shared__ float h1[256];
    __shared__ float h2[128];
    __shared__ float h3[64];
    __shared__ float pr[4];
    if (tid < D_DIM) {
        float s = 0.f;
        const float* zp = z + (size_t)b * L_LEN * D_DIM + tid;
        #pragma unroll 10
        for (int l = 0; l < L_LEN; ++l) s += zp[(size_t)l * D_DIM];
        xb[tid] = s * (1.0f / (float)L_LEN);
    } else if (tid < DIN) {
        xb[tid] = cond[b * C_DIM + (tid - D_DIM)];
    }
    __syncthreads();
    {   // h1: (160)->(256)
        float acc = b1[tid];
        for (int i = 0; i < DIN; ++i) acc += xb[i] * W1[i * 256 + tid];
        h1[tid] = fmaxf(acc, 0.f);
    }
    __syncthreads();
    if (tid < 128) {
        float acc = b2[tid];
        for (int i = 0; i < 256; ++i) acc += h1[i] * W2[i * 128 + tid];
        h2[tid] = fmaxf(acc, 0.f);
    }
    __syncthreads();
    if (tid < 64) {
        float acc = b3[tid];
        for (int i = 0; i < 128; ++i) acc += h2[i] * W3[i * 64 + tid];
        h3[tid] = fmaxf(acc, 0.f);
    }
    __syncthreads();
    if (tid < 4) {
        float acc = b4[tid];
        for (int i = 0; i < 64; ++i) acc += h3[i] * W4[i * 4 + tid];
        pr[tid] = acc;
    }
    __syncthreads();
    if (tid == 0) {
        float num_voices = 1.0f + 14.0f / (1.0f + __expf(-pr[0]));
        float spread     = 1.0f / (1.0f + __expf(-pr[2]));
        float depth      = 0.5f / (1.0f + __expf(-pr[3]));
        float* Pb = P + b * 40;
        float msum = 0.f;
        for (int v = 0; v < NV; ++v) {
            float m = 1.0f / (1.0f + __expf(-(num_voices - (float)v) * 2.0f));
            msum += m;
            Pb[2 + v] = m;
            float pos = ((float)v - 7.5f) * (1.0f / 16.0f);
            Pb[2 + NV + v] = 1.0f - fabsf(pos) * spread * 0.5f;
        }
        float norm = sqrtf(msum + 1e-6f);
        Pb[0] = depth;
        Pb[1] = 1.0f / (norm + 1e-6f);
    }
}

// ---------------- Kernel 2: conv1 (K=7, 160 -> 128) + relu ----------------
// grid = B*16 blocks, 256 threads = 128 oc x 2 l-halves, 8 l per thread
__global__ void conv1_kernel(const float* __restrict__ z, const float* __restrict__ cond,
                             const float* __restrict__ K1, const float* __restrict__ cb1,
                             float* __restrict__ g1) {
    const int NB = 16;
    int b  = blockIdx.x / NB;
    int lt = blockIdx.x % NB;
    int l0 = lt * LT;
    int tid = threadIdx.x;
    __shared__ float sm[DIN][LT + 6];   // [i][p_local], p = l0-3+p_local
    for (int idx = tid; idx < (LT + 6) * DIN; idx += 256) {
        int pl = idx / DIN;
        int i  = idx - pl * DIN;
        int p  = l0 - 3 + pl;
        float v = 0.f;
        if (p >= 0 && p < L_LEN)
            v = (i < D_DIM) ? z[((size_t)b * L_LEN + p) * D_DIM + i]
                            : cond[b * C_DIM + (i - D_DIM)];
        sm[i][pl] = v;
    }
    __syncthreads();
    int oc = tid & 127;
    int lh = tid >> 7;
    int lb = lh * 8;
    float bias = cb1[oc];
    float acc[8];
    #pragma unroll
    for (int j = 0; j < 8; ++j) acc[j] = bias;
    for (int i = 0; i < DIN; ++i) {
        float zr[14];
        #pragma unroll
        for (int q = 0; q < 14; ++q) zr[q] = sm[i][lb + q];
        #pragma unroll
        for (int tap = 0; tap < 7; ++tap) {
            float k = K1[(size_t)(tap * DIN + i) * 128 + oc];
            #pragma unroll
            for (int j = 0; j < 8; ++j) acc[j] += zr[tap + j] * k;
        }
    }
    #pragma unroll
    for (int j = 0; j < 8; ++j) {
        int l = l0 + lb + j;
        if (l < L_LEN) g1[((size_t)b * L_LEN + l) * 128 + oc] = fmaxf(acc[j], 0.f);
    }
}

// ---------------- Kernel 3: conv2 (K=5, 128 -> 64) + relu ----------------
// grid = B*16, 256 threads = 64 oc x 4 l-quarters, 4 l per thread
__global__ void conv2_kernel(const float* __restrict__ g1,
                             const float* __restrict__ K2, const float* __restrict__ cb2,
                             float* __restrict__ g2) {
    const int NB = 16;
    int b  = blockIdx.x / NB;
    int lt = blockIdx.x % NB;
    int l0 = lt * LT;
    int tid = threadIdx.x;
    __shared__ float sm[128][LT + 4];   // p = l0-2+p_local
    for (int idx = tid; idx < (LT + 4) * 128; idx += 256) {
        int pl = idx >> 7;
        int i  = idx & 127;
        int p  = l0 - 2 + pl;
        float v = (p >= 0 && p < L_LEN) ? g1[((size_t)b * L_LEN + p) * 128 + i] : 0.f;
        sm[i][pl] = v;
    }
    __syncthreads();
    int oc = tid & 63;
    int lh = tid >> 6;
    int lb = lh * 4;
    float bias = cb2[oc];
    float acc[4];
    #pragma unroll
    for (int j = 0; j < 4; ++j) acc[j] = bias;
    for (int i = 0; i < 128; ++i) {
        float zr[8];
        #pragma unroll
        for (int q = 0; q < 8; ++q) zr[q] = sm[i][lb + q];
        #pragma unroll
        for (int tap = 0; tap < 5; ++tap) {
            float k = K2[(size_t)(tap * 128 + i) * 64 + oc];
            #pragma unroll
            for (int j = 0; j < 4; ++j) acc[j] += zr[tap + j] * k;
        }
    }
    #pragma unroll
    for (int j = 0; j < 4; ++j) {
        int l = l0 + lb + j;
        if (l < L_LEN) g2[((size_t)b * L_LEN + l) * 64 + oc] = fmaxf(acc[j], 0.f);
    }
}

// ---------------- Kernel 4: conv3 (K=3, 64 -> 16), no act ----------------
// grid = B*16, 256 threads = 16 v x 16 l
__global__ void conv3_kernel(const float* __restrict__ g2,
                             const float* __restrict__ K3, const float* __restrict__ cb3,
                             float* __restrict__ g3) {
    const int NB = 16;
    int b  = blockIdx.x / NB;
    int lt = blockIdx.x % NB;
    int l0 = lt * 16;
    int tid = threadIdx.x;
    int v  = tid & 15;
    int ll = tid >> 4;
    int l  = l0 + ll;
    if (l >= L_LEN) return;
    float acc = cb3[v];
    #pragma unroll
    for (int tap = 0; tap < 3; ++tap) {
        int p = l + tap - 1;
        if (p < 0 || p >= L_LEN) continue;
        const float* gp = g2 + ((size_t)b * L_LEN + p) * 64;
        #pragma unroll
        for (int i = 0; i < 64; ++i) acc += gp[i] * K3[(size_t)(tap * 64 + i) * 16 + v];
    }
    g3[((size_t)b * L_LEN + l) * 16 + v] = acc;
}

// ---------------- Kernel 5: upsample + softplus + unison mix ----------------
__global__ void main_kernel(const float* __restrict__ base, const float* __restrict__ g3,
                            const float* __restrict__ P, float* __restrict__ out) {
    const int CB = (T_LEN + 255) / 256;   // 244
    int b = blockIdx.x / CB;
    int c = blockIdx.x % CB;
    int t = c * 256 + threadIdx.x;
    __shared__ float Pb[34];
    if (threadIdx.x < 34) Pb[threadIdx.x] = P[b * 40 + threadIdx.x];
    __syncthreads();
    if (t >= T_LEN) return;
    float depth = Pb[0];
    float coef  = Pb[1];
    const float scale = 250.0f / 62400.0f;
    float src = ((float)t + 0.5f) * scale - 0.5f;
    src = fminf(fmaxf(src, 0.0f), 249.0f);
    float fi0 = floorf(src);
    int i0 = (int)fi0;
    int i1 = min(i0 + 1, L_LEN - 1);
    float frac = src - fi0;
    const float* r0 = g3 + ((size_t)b * L_LEN + i0) * NV;
    const float* r1 = g3 + ((size_t)b * L_LEN + i1) * NV;
    float tsec = (float)t * (1.0f / 48000.0f);
    const float* bs = base + (size_t)b * T_LEN;
    const int shifts[NV] = {-9,-8,-6,-5,-4,-3,-1,0,0,1,3,4,5,6,8,9};
    float gain_sum = 0.f, uni = 0.f;
    #pragma unroll
    for (int v = 0; v < NV; ++v) {
        float a = r0[v], d = r1[v];
        float vg = a * (1.0f - frac) + d * frac;
        float sp = fmaxf(vg, 0.f) + log1pf(__expf(-fabsf(vg)));   // softplus
        float fv = 3.0f + 0.3f * (float)v;
        float ph = fv * tsec;
        ph -= floorf(ph);
        float lfo = __sinf(6.283185307179586f * ph);
        int tb = t - shifts[v];
        if (tb < 0) tb += T_LEN; else if (tb >= T_LEN) tb -= T_LEN;
        float mod = bs[tb] * (1.0f + 0.2f * depth * lfo);
        gain_sum += sp * Pb[2 + v];
        uni      += mod * sp * Pb[2 + NV + v];
    }
    out[(size_t)b * T_LEN + t] = gain_sum * coef * uni;
}

extern "C" void kernel_launch(void* const* d_in, const int* in_sizes, int n_in,
                              void* d_out, int out_size, void* d_ws, size_t ws_size,
                              hipStream_t stream) {
    const float* base = (const float*)d_in[0];
    const float* z    = (const float*)d_in[1];
    const float* cond = (const float*)d_in[2];
    // d_in[3] fundamental_freq: unused by reference
    const float* W1 = (const float*)d_in[4];  const float* b1 = (const float*)d_in[5];
    const float* W2 = (const float*)d_in[6];  const float* b2 = (const float*)d_in[7];
    const float* W3 = (const float*)d_in[8];  const float* b3 = (const float*)d_in[9];
    const float* W4 = (const float*)d_in[10]; const float* b4 = (const float*)d_in[11];
    const float* K1 = (const float*)d_in[12]; const float* cb1 = (const float*)d_in[13];
    const float* K2 = (const float*)d_in[14]; const float* cb2 = (const float*)d_in[15];
    const float* K3 = (const float*)d_in[16]; const float* cb3 = (const float*)d_in[17];
    float* out = (float*)d_out;

    int B = in_sizes[0] / T_LEN;   // 16

    float* ws = (float*)d_ws;
    float* P  = ws;                         // B*40
    float* g1 = ws + 1024;                  // B*250*128
    float* g2 = g1 + (size_t)B * L_LEN * 128;
    float* g3 = g2 + (size_t)B * L_LEN * 64;

    params_kernel<<<B, 256, 0, stream>>>(z, cond, W1, b1, W2, b2, W3, b3, W4, b4, P);
    conv1_kernel<<<B * 16, 256, 0, stream>>>(z, cond, K1, cb1, g1);
    conv2_kernel<<<B * 16, 256, 0, stream>>>(g1, K2, cb2, g2);
    conv3_kernel<<<B * 16, 256, 0, stream>>>(g2, K3, cb3, g3);
    const int CB = (T_LEN + 255) / 256;
    main_kernel<<<B * CB, 256, 0, stream>>>(base, g3, P, out);
}

// Round 2
// 98.713 us; speedup vs baseline: 1.4668x; 1.4668x over previous
//
#include <hip/hip_runtime.h>
#include <hip/hip_bf16.h>
#include <math.h>

#define L_LEN 250
#define D_DIM 128
#define C_DIM 32
#define DIN   160
#define NV    16
#define T_LEN 62400

// ---------------- Kernel 1: z-mean + MLP -> per-batch params ----------------
// P layout per batch (40 floats): [0]=depth, [1]=coef=1/(norm+1e-6),
// [2..17]=mask[v], [18..33]=pan[v]
__global__ void params_kernel(const float* __restrict__ z, const float* __restrict__ cond,
                              const float* __restrict__ W1, const float* __restrict__ b1,
                              const float* __restrict__ W2, const float* __restrict__ b2,
                              const float* __restrict__ W3, const float* __restrict__ b3,
                              const float* __restrict__ W4, const float* __restrict__ b4,
                              float* __restrict__ P) {
    int b = blockIdx.x;
    int tid = threadIdx.x;
    __shared__ float xb[DIN];
    __shared__ float zp2[128];
    __shared__ float h1[256];
    __shared__ float h2[128];
    __shared__ float h3[64];
    __shared__ float pr[4];
    {   // z-mean, 2-way split over l
        int i = tid & 127, half = tid >> 7;
        const float* zp = z + (size_t)b * L_LEN * D_DIM + i;
        float s = 0.f;
        for (int l = half; l < L_LEN; l += 2) s += zp[(size_t)l * D_DIM];
        if (half) zp2[i] = s;
        __syncthreads();
        if (!half) xb[i] = (s + zp2[i]) * (1.0f / (float)L_LEN);
        if (tid >= 128 && tid < DIN) xb[tid] = cond[b * C_DIM + (tid - 128)];
    }
    __syncthreads();
    {   // h1: (160)->(256)
        float acc = b1[tid];
        for (int i = 0; i < DIN; ++i) acc = fmaf(xb[i], W1[i * 256 + tid], acc);
        h1[tid] = fmaxf(acc, 0.f);
    }
    __syncthreads();
    if (tid < 128) {
        float acc = b2[tid];
        for (int i = 0; i < 256; ++i) acc = fmaf(h1[i], W2[i * 128 + tid], acc);
        h2[tid] = fmaxf(acc, 0.f);
    }
    __syncthreads();
    if (tid < 64) {
        float acc = b3[tid];
        for (int i = 0; i < 128; ++i) acc = fmaf(h2[i], W3[i * 64 + tid], acc);
        h3[tid] = fmaxf(acc, 0.f);
    }
    __syncthreads();
    if (tid < 4) {
        float acc = b4[tid];
        for (int i = 0; i < 64; ++i) acc = fmaf(h3[i], W4[i * 4 + tid], acc);
        pr[tid] = acc;
    }
    __syncthreads();
    if (tid == 0) {
        float num_voices = 1.0f + 14.0f / (1.0f + __expf(-pr[0]));
        float spread     = 1.0f / (1.0f + __expf(-pr[2]));
        float depth      = 0.5f / (1.0f + __expf(-pr[3]));
        float* Pb = P + b * 40;
        float msum = 0.f;
        for (int v = 0; v < NV; ++v) {
            float m = 1.0f / (1.0f + __expf(-(num_voices - (float)v) * 2.0f));
            msum += m;
            Pb[2 + v] = m;
            float pos = ((float)v - 7.5f) * (1.0f / 16.0f);
            Pb[2 + NV + v] = 1.0f - fabsf(pos) * spread * 0.5f;
        }
        float norm = sqrtf(msum + 1e-6f);
        Pb[0] = depth;
        Pb[1] = 1.0f / (norm + 1e-6f);
    }
}

// ---------------- conv1 split-K: grid = 4 * 16b * 16lt = 1024 blocks --------
// Each block: 16 l x 128 oc x 40 ic (no bias; bias+relu+reduce folded into conv2 load)
__global__ __launch_bounds__(256) void conv1_split_kernel(
        const float* __restrict__ z, const float* __restrict__ cond,
        const float* __restrict__ K1, float* __restrict__ parts1) {
    int blk = blockIdx.x;
    int s  = blk >> 8;           // ic split 0..3
    int b  = (blk >> 4) & 15;
    int lt = blk & 15;
    int l0 = lt * 16;
    int tid = threadIdx.x;
    __shared__ float sm[40][28];  // [ic_local][pl], pl: p = l0-3+pl, 0..21; stride 28 for 16B align
    for (int idx = tid; idx < 22 * 40; idx += 256) {
        int pl = idx / 40;
        int il = idx - pl * 40;
        int p  = l0 - 3 + pl;
        int gi = s * 40 + il;
        float v = 0.f;
        if (p >= 0 && p < L_LEN)
            v = (gi < D_DIM) ? z[((size_t)b * L_LEN + p) * D_DIM + gi]
                             : cond[b * C_DIM + (gi - D_DIM)];
        sm[il][pl] = v;
    }
    __syncthreads();
    int oc = tid & 127;
    int lb = (tid >> 7) * 8;
    float acc[8];
    #pragma unroll
    for (int j = 0; j < 8; ++j) acc[j] = 0.f;
    const float* kbase = K1 + (size_t)(s * 40) * 128 + oc;
    for (int il = 0; il < 40; ++il) {
        float zr[16];
        *(float4*)&zr[0]  = *(const float4*)&sm[il][lb];
        *(float4*)&zr[4]  = *(const float4*)&sm[il][lb + 4];
        *(float4*)&zr[8]  = *(const float4*)&sm[il][lb + 8];
        *(float4*)&zr[12] = *(const float4*)&sm[il][lb + 12];
        const float* kp = kbase + (size_t)il * 128;
        #pragma unroll
        for (int tap = 0; tap < 7; ++tap) {
            float k = kp[(size_t)tap * DIN * 128];
            #pragma unroll
            for (int j = 0; j < 8; ++j) acc[j] = fmaf(zr[tap + j], k, acc[j]);
        }
    }
    float* po = parts1 + (size_t)s * (16 * L_LEN * 128) + ((size_t)b * L_LEN) * 128 + oc;
    #pragma unroll
    for (int j = 0; j < 8; ++j) {
        int l = l0 + lb + j;
        if (l < L_LEN) po[(size_t)l * 128] = acc[j];
    }
}

// ---------------- conv2 split-K: grid = 2 * 16b * 16lt = 512 blocks ---------
// Block: 16 l x 64 oc x 64 ic. Input = relu(cb1 + sum parts1). Output partials.
__global__ __launch_bounds__(256) void conv2_split_kernel(
        const float* __restrict__ parts1, const float* __restrict__ cb1,
        const float* __restrict__ K2, float* __restrict__ parts2) {
    int blk = blockIdx.x;
    int h  = blk >> 8;           // ic split 0..1
    int b  = (blk >> 4) & 15;
    int lt = blk & 15;
    int l0 = lt * 16;
    int tid = threadIdx.x;
    const int PSTR = 16 * L_LEN * 128;
    __shared__ float sm[64][28];  // [ic_local][pl], pl: p = l0-2+pl, 0..19
    for (int idx = tid; idx < 20 * 64; idx += 256) {
        int pl = idx >> 6;
        int il = idx & 63;
        int p  = l0 - 2 + pl;
        int gi = h * 64 + il;
        float v = 0.f;
        if (p >= 0 && p < L_LEN) {
            size_t o = ((size_t)b * L_LEN + p) * 128 + gi;
            v = cb1[gi] + parts1[o] + parts1[o + PSTR] + parts1[o + 2 * PSTR] + parts1[o + 3 * PSTR];
            v = fmaxf(v, 0.f);
        }
        sm[il][pl] = v;
    }
    __syncthreads();
    int oc = tid & 63;
    int lb = (tid >> 6) * 4;
    float acc[4];
    #pragma unroll
    for (int j = 0; j < 4; ++j) acc[j] = 0.f;
    const float* kbase = K2 + (size_t)(h * 64) * 64 + oc;
    for (int il = 0; il < 64; ++il) {
        float zr[8];
        *(float4*)&zr[0] = *(const float4*)&sm[il][lb];
        *(float4*)&zr[4] = *(const float4*)&sm[il][lb + 4];
        const float* kp = kbase + (size_t)il * 64;
        #pragma unroll
        for (int tap = 0; tap < 5; ++tap) {
            float k = kp[(size_t)tap * 128 * 64];
            #pragma unroll
            for (int j = 0; j < 4; ++j) acc[j] = fmaf(zr[tap + j], k, acc[j]);
        }
    }
    float* po = parts2 + (size_t)h * (16 * L_LEN * 64) + ((size_t)b * L_LEN) * 64 + oc;
    #pragma unroll
    for (int j = 0; j < 4; ++j) {
        int l = l0 + lb + j;
        if (l < L_LEN) po[(size_t)l * 64] = acc[j];
    }
}

// ---------------- conv3: grid = 256 blocks, LDS-staged weights + inputs -----
__global__ __launch_bounds__(256) void conv3_kernel(
        const float* __restrict__ parts2, const float* __restrict__ cb2,
        const float* __restrict__ K3, const float* __restrict__ cb3,
        float* __restrict__ g3) {
    int b  = blockIdx.x >> 4;
    int lt = blockIdx.x & 15;
    int l0 = lt * 16;
    int tid = threadIdx.x;
    const int PSTR2 = 16 * L_LEN * 64;
    __shared__ float sm2[18][68];   // [pl][ic], p = l0-1+pl
    __shared__ float k3t[16][196];  // [v][tap*64+ic]
    for (int idx = tid; idx < 3 * 64 * 16; idx += 256) {
        int v  = idx & 15;
        int ti = idx >> 4;
        k3t[v][ti] = K3[ti * 16 + v];
    }
    for (int idx = tid; idx < 18 * 64; idx += 256) {
        int pl = idx >> 6;
        int i  = idx & 63;
        int p  = l0 - 1 + pl;
        float v = 0.f;
        if (p >= 0 && p < L_LEN) {
            size_t o = ((size_t)b * L_LEN + p) * 64 + i;
            v = fmaxf(cb2[i] + parts2[o] + parts2[o + PSTR2], 0.f);
        }
        sm2[pl][i] = v;
    }
    __syncthreads();
    int v  = tid & 15;
    int lq = tid >> 4;
    int l  = l0 + lq;
    float acc = cb3[v];
    #pragma unroll
    for (int tap = 0; tap < 3; ++tap) {
        #pragma unroll
        for (int i4 = 0; i4 < 16; ++i4) {
            float4 g = *(const float4*)&sm2[lq + tap][i4 * 4];
            float4 k = *(const float4*)&k3t[v][tap * 64 + i4 * 4];
            acc = fmaf(g.x, k.x, acc);
            acc = fmaf(g.y, k.y, acc);
            acc = fmaf(g.z, k.z, acc);
            acc = fmaf(g.w, k.w, acc);
        }
    }
    if (l < L_LEN) g3[((size_t)b * L_LEN + l) * NV + v] = acc;
}

// ---------------- main: upsample + softplus + unison mix --------------------
__global__ __launch_bounds__(256) void main_kernel(
        const float* __restrict__ base, const float* __restrict__ g3,
        const float* __restrict__ P, float* __restrict__ out) {
    const int CB = (T_LEN + 255) / 256;   // 244
    int b = blockIdx.x / CB;
    int c = blockIdx.x % CB;
    int t = c * 256 + threadIdx.x;
    __shared__ float Pb[34];
    if (threadIdx.x < 34) Pb[threadIdx.x] = P[b * 40 + threadIdx.x];
    __syncthreads();
    if (t >= T_LEN) return;
    float depth = Pb[0];
    float coef  = Pb[1];
    const float scale = 250.0f / 62400.0f;
    float src = ((float)t + 0.5f) * scale - 0.5f;
    src = fminf(fmaxf(src, 0.0f), 249.0f);
    float fi0 = floorf(src);
    int i0 = (int)fi0;
    int i1 = min(i0 + 1, L_LEN - 1);
    float frac = src - fi0;
    const float4* r0 = (const float4*)(g3 + ((size_t)b * L_LEN + i0) * NV);
    const float4* r1 = (const float4*)(g3 + ((size_t)b * L_LEN + i1) * NV);
    float vg[16];
    #pragma unroll
    for (int q = 0; q < 4; ++q) {
        float4 a = r0[q];
        float4 d = r1[q];
        vg[q * 4 + 0] = fmaf(d.x - a.x, frac, a.x);
        vg[q * 4 + 1] = fmaf(d.y - a.y, frac, a.y);
        vg[q * 4 + 2] = fmaf(d.z - a.z, frac, a.z);
        vg[q * 4 + 3] = fmaf(d.w - a.w, frac, a.w);
    }
    float tsec = (float)t * (1.0f / 48000.0f);
    const float* bs = base + (size_t)b * T_LEN;
    const int shifts[NV] = {-9,-8,-6,-5,-4,-3,-1,0,0,1,3,4,5,6,8,9};
    float gain_sum = 0.f, uni = 0.f;
    #pragma unroll
    for (int v = 0; v < NV; ++v) {
        float x = vg[v];
        float sp = fmaxf(x, 0.f) + __logf(1.0f + __expf(-fabsf(x)));   // softplus
        float fv = 3.0f + 0.3f * (float)v;
        float ph = fv * tsec;
        ph -= floorf(ph);
        float lfo = __sinf(6.283185307179586f * ph);
        int tb = t - shifts[v];
        if (tb < 0) tb += T_LEN; else if (tb >= T_LEN) tb -= T_LEN;
        float mod = bs[tb] * fmaf(0.2f * depth, lfo, 1.0f);
        gain_sum = fmaf(sp, Pb[2 + v], gain_sum);
        uni      = fmaf(mod * sp, Pb[2 + NV + v], uni);
    }
    out[(size_t)b * T_LEN + t] = gain_sum * coef * uni;
}

// ================= fallback (round-1 monolithic) kernels ====================
__global__ void conv1_mono_kernel(const float* __restrict__ z, const float* __restrict__ cond,
                                  const float* __restrict__ K1, const float* __restrict__ cb1,
                                  float* __restrict__ g1) {
    int b  = blockIdx.x >> 4;
    int lt = blockIdx.x & 15;
    int l0 = lt * 16;
    int tid = threadIdx.x;
    __shared__ float sm[DIN][22];
    for (int idx = tid; idx < 22 * DIN; idx += 256) {
        int pl = idx / DIN;
        int i  = idx - pl * DIN;
        int p  = l0 - 3 + pl;
        float v = 0.f;
        if (p >= 0 && p < L_LEN)
            v = (i < D_DIM) ? z[((size_t)b * L_LEN + p) * D_DIM + i]
                            : cond[b * C_DIM + (i - D_DIM)];
        sm[i][pl] = v;
    }
    __syncthreads();
    int oc = tid & 127;
    int lb = (tid >> 7) * 8;
    float bias = cb1[oc];
    float acc[8];
    #pragma unroll
    for (int j = 0; j < 8; ++j) acc[j] = bias;
    for (int i = 0; i < DIN; ++i) {
        float zr[14];
        #pragma unroll
        for (int q = 0; q < 14; ++q) zr[q] = sm[i][lb + q];
        #pragma unroll
        for (int tap = 0; tap < 7; ++tap) {
            float k = K1[(size_t)(tap * DIN + i) * 128 + oc];
            #pragma unroll
            for (int j = 0; j < 8; ++j) acc[j] = fmaf(zr[tap + j], k, acc[j]);
        }
    }
    #pragma unroll
    for (int j = 0; j < 8; ++j) {
        int l = l0 + lb + j;
        if (l < L_LEN) g1[((size_t)b * L_LEN + l) * 128 + oc] = fmaxf(acc[j], 0.f);
    }
}

__global__ void conv2_mono_kernel(const float* __restrict__ g1,
                                  const float* __restrict__ K2, const float* __restrict__ cb2,
                                  float* __restrict__ g2) {
    int b  = blockIdx.x >> 4;
    int lt = blockIdx.x & 15;
    int l0 = lt * 16;
    int tid = threadIdx.x;
    __shared__ float sm[128][20];
    for (int idx = tid; idx < 20 * 128; idx += 256) {
        int pl = idx >> 7;
        int i  = idx & 127;
        int p  = l0 - 2 + pl;
        float v = (p >= 0 && p < L_LEN) ? g1[((size_t)b * L_LEN + p) * 128 + i] : 0.f;
        sm[i][pl] = v;
    }
    __syncthreads();
    int oc = tid & 63;
    int lb = (tid >> 6) * 4;
    float bias = cb2[oc];
    float acc[4];
    #pragma unroll
    for (int j = 0; j < 4; ++j) acc[j] = bias;
    for (int i = 0; i < 128; ++i) {
        float zr[8];
        #pragma unroll
        for (int q = 0; q < 8; ++q) zr[q] = sm[i][lb + q];
        #pragma unroll
        for (int tap = 0; tap < 5; ++tap) {
            float k = K2[(size_t)(tap * 128 + i) * 64 + oc];
            #pragma unroll
            for (int j = 0; j < 4; ++j) acc[j] = fmaf(zr[tap + j], k, acc[j]);
        }
    }
    #pragma unroll
    for (int j = 0; j < 4; ++j) {
        int l = l0 + lb + j;
        if (l < L_LEN) g2[((size_t)b * L_LEN + l) * 64 + oc] = fmaxf(acc[j], 0.f);
    }
}

__global__ void conv3_mono_kernel(const float* __restrict__ g2,
                                  const float* __restrict__ K3, const float* __restrict__ cb3,
                                  float* __restrict__ g3) {
    int b  = blockIdx.x >> 4;
    int lt = blockIdx.x & 15;
    int l0 = lt * 16;
    int tid = threadIdx.x;
    int v  = tid & 15;
    int ll = tid >> 4;
    int l  = l0 + ll;
    if (l >= L_LEN) return;
    float acc = cb3[v];
    #pragma unroll
    for (int tap = 0; tap < 3; ++tap) {
        int p = l + tap - 1;
        if (p < 0 || p >= L_LEN) continue;
        const float* gp = g2 + ((size_t)b * L_LEN + p) * 64;
        #pragma unroll
        for (int i = 0; i < 64; ++i) acc = fmaf(gp[i], K3[(size_t)(tap * 64 + i) * 16 + v], acc);
    }
    g3[((size_t)b * L_LEN + l) * 16 + v] = acc;
}

extern "C" void kernel_launch(void* const* d_in, const int* in_sizes, int n_in,
                              void* d_out, int out_size, void* d_ws, size_t ws_size,
                              hipStream_t stream) {
    const float* base = (const float*)d_in[0];
    const float* z    = (const float*)d_in[1];
    const float* cond = (const float*)d_in[2];
    const float* W1 = (const float*)d_in[4];  const float* b1 = (const float*)d_in[5];
    const float* W2 = (const float*)d_in[6];  const float* b2 = (const float*)d_in[7];
    const float* W3 = (const float*)d_in[8];  const float* b3 = (const float*)d_in[9];
    const float* W4 = (const float*)d_in[10]; const float* b4 = (const float*)d_in[11];
    const float* K1 = (const float*)d_in[12]; const float* cb1 = (const float*)d_in[13];
    const float* K2 = (const float*)d_in[14]; const float* cb2 = (const float*)d_in[15];
    const float* K3 = (const float*)d_in[16]; const float* cb3 = (const float*)d_in[17];
    float* out = (float*)d_out;

    int B = in_sizes[0] / T_LEN;   // 16
    const int CB = (T_LEN + 255) / 256;

    float* ws = (float*)d_ws;
    const size_t P1 = (size_t)16 * L_LEN * 128;    // 512000 per split
    const size_t P2 = (size_t)16 * L_LEN * 64;     // 256000 per split
    size_t need = (1024 + 4 * P1 + 2 * P2 + (size_t)16 * L_LEN * NV) * sizeof(float);

    float* P = ws;
    if (ws_size >= need) {
        float* parts1 = ws + 1024;
        float* parts2 = parts1 + 4 * P1;
        float* g3     = parts2 + 2 * P2;
        params_kernel<<<B, 256, 0, stream>>>(z, cond, W1, b1, W2, b2, W3, b3, W4, b4, P);
        conv1_split_kernel<<<4 * B * 16, 256, 0, stream>>>(z, cond, K1, parts1);
        conv2_split_kernel<<<2 * B * 16, 256, 0, stream>>>(parts1, cb1, K2, parts2);
        conv3_kernel<<<B * 16, 256, 0, stream>>>(parts2, cb2, K3, cb3, g3);
        main_kernel<<<B * CB, 256, 0, stream>>>(base, g3, P, out);
    } else {
        float* g1 = ws + 1024;
        float* g2 = g1 + (size_t)B * L_LEN * 128;
        float* g3 = g2 + (size_t)B * L_LEN * 64;
        params_kernel<<<B, 256, 0, stream>>>(z, cond, W1, b1, W2, b2, W3, b3, W4, b4, P);
        conv1_mono_kernel<<<B * 16, 256, 0, stream>>>(z, cond, K1, cb1, g1);
        conv2_mono_kernel<<<B * 16, 256, 0, stream>>>(g1, K2, cb2, g2);
        conv3_mono_kernel<<<B * 16, 256, 0, stream>>>(g2, K3, cb3, g3);
        main_kernel<<<B * CB, 256, 0, stream>>>(base, g3, P, out);
    }
}

// Round 3
// 67.514 us; speedup vs baseline: 2.1446x; 1.4621x over previous
//
#include <hip/hip_runtime.h>
#include <hip/hip_bf16.h>
#include <math.h>

#define L_LEN 250
#define D_DIM 128
#define C_DIM 32
#define DIN   160
#define NV    16
#define T_LEN 62400

// ---------------- zmean: B*10 blocks, partial sums over l ------------------
// zpart[b][s][d], s = l-chunk of 25 rows
__global__ __launch_bounds__(256) void zmean_kernel(const float* __restrict__ z,
                                                    float* __restrict__ zpart) {
    int b = blockIdx.x / 10, s = blockIdx.x % 10;
    int l0 = s * 25;
    int tid = threadIdx.x;
    int d4 = tid & 31, rg = tid >> 5;
    float4 acc = make_float4(0.f, 0.f, 0.f, 0.f);
    const float4* zp = (const float4*)(z + ((size_t)b * L_LEN + l0) * D_DIM) + d4;
    for (int r = rg; r < 25; r += 8) {
        float4 v = zp[(size_t)r * 32];
        acc.x += v.x; acc.y += v.y; acc.z += v.z; acc.w += v.w;
    }
    __shared__ float4 sm[8][32];
    sm[rg][d4] = acc;
    __syncthreads();
    if (rg == 0) {
        #pragma unroll
        for (int g = 1; g < 8; ++g) {
            float4 v = sm[g][d4];
            acc.x += v.x; acc.y += v.y; acc.z += v.z; acc.w += v.w;
        }
        ((float4*)(zpart + ((size_t)b * 10 + s) * 128))[d4] = acc;
    }
}

// ------- conv1 split-K (blocks 0..1023) + per-batch MLP (blocks 1024..1039) -
// P layout per batch (40 floats): [0]=depth, [1]=coef, [2..17]=mask, [18..33]=pan
__global__ __launch_bounds__(256) void conv1_mlp_kernel(
        const float* __restrict__ z, const float* __restrict__ cond,
        const float* __restrict__ K1, float* __restrict__ parts1,
        const float* __restrict__ zpart,
        const float* __restrict__ W1, const float* __restrict__ b1,
        const float* __restrict__ W2, const float* __restrict__ b2,
        const float* __restrict__ W3, const float* __restrict__ b3,
        const float* __restrict__ W4, const float* __restrict__ b4,
        float* __restrict__ P) {
    int tid = threadIdx.x;
    if (blockIdx.x >= 1024) {
        // ---------------- MLP path ----------------
        int b = blockIdx.x - 1024;
        __shared__ float xb[DIN];
        __shared__ float h1[256];
        __shared__ float h2[128];
        __shared__ float h3[64];
        __shared__ float pr[4];
        if (tid < 128) {
            float s = 0.f;
            const float* zp = zpart + (size_t)b * 10 * 128 + tid;
            #pragma unroll
            for (int q = 0; q < 10; ++q) s += zp[q * 128];
            xb[tid] = s * (1.0f / (float)L_LEN);
        } else if (tid < DIN) {
            xb[tid] = cond[b * C_DIM + (tid - 128)];
        }
        __syncthreads();
        {
            float a0 = b1[tid], a1 = 0.f;
            #pragma unroll 8
            for (int i = 0; i < DIN; i += 2) {
                a0 = fmaf(xb[i],     W1[i * 256 + tid],       a0);
                a1 = fmaf(xb[i + 1], W1[(i + 1) * 256 + tid], a1);
            }
            h1[tid] = fmaxf(a0 + a1, 0.f);
        }
        __syncthreads();
        if (tid < 128) {
            float a0 = b2[tid], a1 = 0.f;
            #pragma unroll 8
            for (int i = 0; i < 256; i += 2) {
                a0 = fmaf(h1[i],     W2[i * 128 + tid],       a0);
                a1 = fmaf(h1[i + 1], W2[(i + 1) * 128 + tid], a1);
            }
            h2[tid] = fmaxf(a0 + a1, 0.f);
        }
        __syncthreads();
        if (tid < 64) {
            float a0 = b3[tid], a1 = 0.f;
            #pragma unroll 8
            for (int i = 0; i < 128; i += 2) {
                a0 = fmaf(h2[i],     W3[i * 64 + tid],       a0);
                a1 = fmaf(h2[i + 1], W3[(i + 1) * 64 + tid], a1);
            }
            h3[tid] = fmaxf(a0 + a1, 0.f);
        }
        __syncthreads();
        if (tid < 4) {
            float acc = b4[tid];
            #pragma unroll 8
            for (int i = 0; i < 64; ++i) acc = fmaf(h3[i], W4[i * 4 + tid], acc);
            pr[tid] = acc;
        }
        __syncthreads();
        if (tid == 0) {
            float num_voices = 1.0f + 14.0f / (1.0f + __expf(-pr[0]));
            float spread     = 1.0f / (1.0f + __expf(-pr[2]));
            float depth      = 0.5f / (1.0f + __expf(-pr[3]));
            float* Pb = P + b * 40;
            float msum = 0.f;
            for (int v = 0; v < NV; ++v) {
                float m = 1.0f / (1.0f + __expf(-(num_voices - (float)v) * 2.0f));
                msum += m;
                Pb[2 + v] = m;
                float pos = ((float)v - 7.5f) * (1.0f / 16.0f);
                Pb[2 + NV + v] = 1.0f - fabsf(pos) * spread * 0.5f;
            }
            float norm = sqrtf(msum + 1e-6f);
            Pb[0] = depth;
            Pb[1] = 1.0f / (norm + 1e-6f);
        }
        return;
    }
    // ---------------- conv1 split-K path ----------------
    int blk = blockIdx.x;
    int s  = blk >> 8;           // ic split 0..3
    int b  = (blk >> 4) & 15;
    int lt = blk & 15;
    int l0 = lt * 16;
    __shared__ float smc[40][28];  // [ic_local][pl], p = l0-3+pl, 0..21
    for (int idx = tid; idx < 22 * 40; idx += 256) {
        int pl = idx / 40;
        int il = idx - pl * 40;
        int p  = l0 - 3 + pl;
        int gi = s * 40 + il;
        float v = 0.f;
        if (p >= 0 && p < L_LEN)
            v = (gi < D_DIM) ? z[((size_t)b * L_LEN + p) * D_DIM + gi]
                             : cond[b * C_DIM + (gi - D_DIM)];
        smc[il][pl] = v;
    }
    __syncthreads();
    int oc = tid & 127;
    int lb = (tid >> 7) * 8;
    float acc[8];
    #pragma unroll
    for (int j = 0; j < 8; ++j) acc[j] = 0.f;
    const float* kbase = K1 + (size_t)(s * 40) * 128 + oc;
    for (int il = 0; il < 40; ++il) {
        float zr[16];
        *(float4*)&zr[0]  = *(const float4*)&smc[il][lb];
        *(float4*)&zr[4]  = *(const float4*)&smc[il][lb + 4];
        *(float4*)&zr[8]  = *(const float4*)&smc[il][lb + 8];
        *(float4*)&zr[12] = *(const float4*)&smc[il][lb + 12];
        const float* kp = kbase + (size_t)il * 128;
        #pragma unroll
        for (int tap = 0; tap < 7; ++tap) {
            float k = kp[(size_t)tap * DIN * 128];
            #pragma unroll
            for (int j = 0; j < 8; ++j) acc[j] = fmaf(zr[tap + j], k, acc[j]);
        }
    }
    float* po = parts1 + (size_t)s * (16 * L_LEN * 128) + ((size_t)b * L_LEN) * 128 + oc;
    #pragma unroll
    for (int j = 0; j < 8; ++j) {
        int l = l0 + lb + j;
        if (l < L_LEN) po[(size_t)l * 128] = acc[j];
    }
}

// ---------------- conv2 split-K: grid = 2 * 16b * 16lt = 512 blocks ---------
__global__ __launch_bounds__(256) void conv2_split_kernel(
        const float* __restrict__ parts1, const float* __restrict__ cb1,
        const float* __restrict__ K2, float* __restrict__ parts2) {
    int blk = blockIdx.x;
    int h  = blk >> 8;           // ic split 0..1
    int b  = (blk >> 4) & 15;
    int lt = blk & 15;
    int l0 = lt * 16;
    int tid = threadIdx.x;
    const int PSTR = 16 * L_LEN * 128;
    __shared__ float sm[64][28];  // [ic_local][pl], p = l0-2+pl, 0..19
    for (int idx = tid; idx < 20 * 64; idx += 256) {
        int pl = idx >> 6;
        int il = idx & 63;
        int p  = l0 - 2 + pl;
        int gi = h * 64 + il;
        float v = 0.f;
        if (p >= 0 && p < L_LEN) {
            size_t o = ((size_t)b * L_LEN + p) * 128 + gi;
            v = cb1[gi] + parts1[o] + parts1[o + PSTR] + parts1[o + 2 * PSTR] + parts1[o + 3 * PSTR];
            v = fmaxf(v, 0.f);
        }
        sm[il][pl] = v;
    }
    __syncthreads();
    int oc = tid & 63;
    int lb = (tid >> 6) * 4;
    float acc[4];
    #pragma unroll
    for (int j = 0; j < 4; ++j) acc[j] = 0.f;
    const float* kbase = K2 + (size_t)(h * 64) * 64 + oc;
    for (int il = 0; il < 64; ++il) {
        float zr[8];
        *(float4*)&zr[0] = *(const float4*)&sm[il][lb];
        *(float4*)&zr[4] = *(const float4*)&sm[il][lb + 4];
        const float* kp = kbase + (size_t)il * 64;
        #pragma unroll
        for (int tap = 0; tap < 5; ++tap) {
            float k = kp[(size_t)tap * 128 * 64];
            #pragma unroll
            for (int j = 0; j < 4; ++j) acc[j] = fmaf(zr[tap + j], k, acc[j]);
        }
    }
    float* po = parts2 + (size_t)h * (16 * L_LEN * 64) + ((size_t)b * L_LEN) * 64 + oc;
    #pragma unroll
    for (int j = 0; j < 4; ++j) {
        int l = l0 + lb + j;
        if (l < L_LEN) po[(size_t)l * 64] = acc[j];
    }
}

// ---------------- conv3: grid = 256 blocks ----------------------------------
__global__ __launch_bounds__(256) void conv3_kernel(
        const float* __restrict__ parts2, const float* __restrict__ cb2,
        const float* __restrict__ K3, const float* __restrict__ cb3,
        float* __restrict__ g3) {
    int b  = blockIdx.x >> 4;
    int lt = blockIdx.x & 15;
    int l0 = lt * 16;
    int tid = threadIdx.x;
    const int PSTR2 = 16 * L_LEN * 64;
    __shared__ float sm2[18][68];   // [pl][ic], p = l0-1+pl
    __shared__ float k3t[16][196];  // [v][tap*64+ic]
    for (int idx = tid; idx < 3 * 64 * 16; idx += 256) {
        int v  = idx & 15;
        int ti = idx >> 4;
        k3t[v][ti] = K3[ti * 16 + v];
    }
    for (int idx = tid; idx < 18 * 64; idx += 256) {
        int pl = idx >> 6;
        int i  = idx & 63;
        int p  = l0 - 1 + pl;
        float v = 0.f;
        if (p >= 0 && p < L_LEN) {
            size_t o = ((size_t)b * L_LEN + p) * 64 + i;
            v = fmaxf(cb2[i] + parts2[o] + parts2[o + PSTR2], 0.f);
        }
        sm2[pl][i] = v;
    }
    __syncthreads();
    int v  = tid & 15;
    int lq = tid >> 4;
    int l  = l0 + lq;
    float acc = cb3[v];
    #pragma unroll
    for (int tap = 0; tap < 3; ++tap) {
        #pragma unroll
        for (int i4 = 0; i4 < 16; ++i4) {
            float4 g = *(const float4*)&sm2[lq + tap][i4 * 4];
            float4 k = *(const float4*)&k3t[v][tap * 64 + i4 * 4];
            acc = fmaf(g.x, k.x, acc);
            acc = fmaf(g.y, k.y, acc);
            acc = fmaf(g.z, k.z, acc);
            acc = fmaf(g.w, k.w, acc);
        }
    }
    if (l < L_LEN) g3[((size_t)b * L_LEN + l) * NV + v] = acc;
}

// ---------------- main: upsample + softplus + unison mix --------------------
__global__ __launch_bounds__(256) void main_kernel(
        const float* __restrict__ base, const float* __restrict__ g3,
        const float* __restrict__ P, float* __restrict__ out) {
    const int CB = (T_LEN + 255) / 256;   // 244
    int b = blockIdx.x / CB;
    int c = blockIdx.x % CB;
    int t = c * 256 + threadIdx.x;
    __shared__ float Pb[34];
    if (threadIdx.x < 34) Pb[threadIdx.x] = P[b * 40 + threadIdx.x];
    __syncthreads();
    if (t >= T_LEN) return;
    float depth = Pb[0];
    float coef  = Pb[1];
    const float scale = 250.0f / 62400.0f;
    float src = ((float)t + 0.5f) * scale - 0.5f;
    src = fminf(fmaxf(src, 0.0f), 249.0f);
    float fi0 = floorf(src);
    int i0 = (int)fi0;
    int i1 = min(i0 + 1, L_LEN - 1);
    float frac = src - fi0;
    const float4* r0 = (const float4*)(g3 + ((size_t)b * L_LEN + i0) * NV);
    const float4* r1 = (const float4*)(g3 + ((size_t)b * L_LEN + i1) * NV);
    float vg[16];
    #pragma unroll
    for (int q = 0; q < 4; ++q) {
        float4 a = r0[q];
        float4 d = r1[q];
        vg[q * 4 + 0] = fmaf(d.x - a.x, frac, a.x);
        vg[q * 4 + 1] = fmaf(d.y - a.y, frac, a.y);
        vg[q * 4 + 2] = fmaf(d.z - a.z, frac, a.z);
        vg[q * 4 + 3] = fmaf(d.w - a.w, frac, a.w);
    }
    float tsec = (float)t * (1.0f / 48000.0f);
    const float* bs = base + (size_t)b * T_LEN;
    const int shifts[NV] = {-9,-8,-6,-5,-4,-3,-1,0,0,1,3,4,5,6,8,9};
    float gain_sum = 0.f, uni = 0.f;
    #pragma unroll
    for (int v = 0; v < NV; ++v) {
        float x = vg[v];
        float sp = fmaxf(x, 0.f) + __logf(1.0f + __expf(-fabsf(x)));   // softplus
        float fv = 3.0f + 0.3f * (float)v;
        float ph = fv * tsec;
        ph -= floorf(ph);
        float lfo = __sinf(6.283185307179586f * ph);
        int tb = t - shifts[v];
        if (tb < 0) tb += T_LEN; else if (tb >= T_LEN) tb -= T_LEN;
        float mod = bs[tb] * fmaf(0.2f * depth, lfo, 1.0f);
        gain_sum = fmaf(sp, Pb[2 + v], gain_sum);
        uni      = fmaf(mod * sp, Pb[2 + NV + v], uni);
    }
    out[(size_t)b * T_LEN + t] = gain_sum * coef * uni;
}

// ================= fallback (round-1 monolithic) kernels ====================
__global__ void params_kernel(const float* __restrict__ z, const float* __restrict__ cond,
                              const float* __restrict__ W1, const float* __restrict__ b1,
                              const float* __restrict__ W2, const float* __restrict__ b2,
                              const float* __restrict__ W3, const float* __restrict__ b3,
                              const float* __restrict__ W4, const float* __restrict__ b4,
                              float* __restrict__ P) {
    int b = blockIdx.x;
    int tid = threadIdx.x;
    __shared__ float xb[DIN];
    __shared__ float zp2[128];
    __shared__ float h1[256];
    __shared__ float h2[128];
    __shared__ float h3[64];
    __shared__ float pr[4];
    {
        int i = tid & 127, half = tid >> 7;
        const float* zp = z + (size_t)b * L_LEN * D_DIM + i;
        float s = 0.f;
        for (int l = half; l < L_LEN; l += 2) s += zp[(size_t)l * D_DIM];
        if (half) zp2[i] = s;
        __syncthreads();
        if (!half) xb[i] = (s + zp2[i]) * (1.0f / (float)L_LEN);
        if (tid >= 128 && tid < DIN) xb[tid] = cond[b * C_DIM + (tid - 128)];
    }
    __syncthreads();
    {
        float acc = b1[tid];
        for (int i = 0; i < DIN; ++i) acc = fmaf(xb[i], W1[i * 256 + tid], acc);
        h1[tid] = fmaxf(acc, 0.f);
    }
    __syncthreads();
    if (tid < 128) {
        float acc = b2[tid];
        for (int i = 0; i < 256; ++i) acc = fmaf(h1[i], W2[i * 128 + tid], acc);
        h2[tid] = fmaxf(acc, 0.f);
    }
    __syncthreads();
    if (tid < 64) {
        float acc = b3[tid];
        for (int i = 0; i < 128; ++i) acc = fmaf(h2[i], W3[i * 64 + tid], acc);
        h3[tid] = fmaxf(acc, 0.f);
    }
    __syncthreads();
    if (tid < 4) {
        float acc = b4[tid];
        for (int i = 0; i < 64; ++i) acc = fmaf(h3[i], W4[i * 4 + tid], acc);
        pr[tid] = acc;
    }
    __syncthreads();
    if (tid == 0) {
        float num_voices = 1.0f + 14.0f / (1.0f + __expf(-pr[0]));
        float spread     = 1.0f / (1.0f + __expf(-pr[2]));
        float depth      = 0.5f / (1.0f + __expf(-pr[3]));
        float* Pb = P + b * 40;
        float msum = 0.f;
        for (int v = 0; v < NV; ++v) {
            float m = 1.0f / (1.0f + __expf(-(num_voices - (float)v) * 2.0f));
            msum += m;
            Pb[2 + v] = m;
            float pos = ((float)v - 7.5f) * (1.0f / 16.0f);
            Pb[2 + NV + v] = 1.0f - fabsf(pos) * spread * 0.5f;
        }
        float norm = sqrtf(msum + 1e-6f);
        Pb[0] = depth;
        Pb[1] = 1.0f / (norm + 1e-6f);
    }
}

__global__ void conv1_mono_kernel(const float* __restrict__ z, const float* __restrict__ cond,
                                  const float* __restrict__ K1, const float* __restrict__ cb1,
                                  float* __restrict__ g1) {
    int b  = blockIdx.x >> 4;
    int lt = blockIdx.x & 15;
    int l0 = lt * 16;
    int tid = threadIdx.x;
    __shared__ float sm[DIN][22];
    for (int idx = tid; idx < 22 * DIN; idx += 256) {
        int pl = idx / DIN;
        int i  = idx - pl * DIN;
        int p  = l0 - 3 + pl;
        float v = 0.f;
        if (p >= 0 && p < L_LEN)
            v = (i < D_DIM) ? z[((size_t)b * L_LEN + p) * D_DIM + i]
                            : cond[b * C_DIM + (i - D_DIM)];
        sm[i][pl] = v;
    }
    __syncthreads();
    int oc = tid & 127;
    int lb = (tid >> 7) * 8;
    float bias = cb1[oc];
    float acc[8];
    #pragma unroll
    for (int j = 0; j < 8; ++j) acc[j] = bias;
    for (int i = 0; i < DIN; ++i) {
        float zr[14];
        #pragma unroll
        for (int q = 0; q < 14; ++q) zr[q] = sm[i][lb + q];
        #pragma unroll
        for (int tap = 0; tap < 7; ++tap) {
            float k = K1[(size_t)(tap * DIN + i) * 128 + oc];
            #pragma unroll
            for (int j = 0; j < 8; ++j) acc[j] = fmaf(zr[tap + j], k, acc[j]);
        }
    }
    #pragma unroll
    for (int j = 0; j < 8; ++j) {
        int l = l0 + lb + j;
        if (l < L_LEN) g1[((size_t)b * L_LEN + l) * 128 + oc] = fmaxf(acc[j], 0.f);
    }
}

__global__ void conv2_mono_kernel(const float* __restrict__ g1,
                                  const float* __restrict__ K2, const float* __restrict__ cb2,
                                  float* __restrict__ g2) {
    int b  = blockIdx.x >> 4;
    int lt = blockIdx.x & 15;
    int l0 = lt * 16;
    int tid = threadIdx.x;
    __shared__ float sm[128][20];
    for (int idx = tid; idx < 20 * 128; idx += 256) {
        int pl = idx >> 7;
        int i  = idx & 127;
        int p  = l0 - 2 + pl;
        float v = (p >= 0 && p < L_LEN) ? g1[((size_t)b * L_LEN + p) * 128 + i] : 0.f;
        sm[i][pl] = v;
    }
    __syncthreads();
    int oc = tid & 63;
    int lb = (tid >> 6) * 4;
    float bias = cb2[oc];
    float acc[4];
    #pragma unroll
    for (int j = 0; j < 4; ++j) acc[j] = bias;
    for (int i = 0; i < 128; ++i) {
        float zr[8];
        #pragma unroll
        for (int q = 0; q < 8; ++q) zr[q] = sm[i][lb + q];
        #pragma unroll
        for (int tap = 0; tap < 5; ++tap) {
            float k = K2[(size_t)(tap * 128 + i) * 64 + oc];
            #pragma unroll
            for (int j = 0; j < 4; ++j) acc[j] = fmaf(zr[tap + j], k, acc[j]);
        }
    }
    #pragma unroll
    for (int j = 0; j < 4; ++j) {
        int l = l0 + lb + j;
        if (l < L_LEN) g2[((size_t)b * L_LEN + l) * 64 + oc] = fmaxf(acc[j], 0.f);
    }
}

__global__ void conv3_mono_kernel(const float* __restrict__ g2,
                                  const float* __restrict__ K3, const float* __restrict__ cb3,
                                  float* __restrict__ g3) {
    int b  = blockIdx.x >> 4;
    int lt = blockIdx.x & 15;
    int l0 = lt * 16;
    int tid = threadIdx.x;
    int v  = tid & 15;
    int ll = tid >> 4;
    int l  = l0 + ll;
    if (l >= L_LEN) return;
    float acc = cb3[v];
    #pragma unroll
    for (int tap = 0; tap < 3; ++tap) {
        int p = l + tap - 1;
        if (p < 0 || p >= L_LEN) continue;
        const float* gp = g2 + ((size_t)b * L_LEN + p) * 64;
        #pragma unroll
        for (int i = 0; i < 64; ++i) acc = fmaf(gp[i], K3[(size_t)(tap * 64 + i) * 16 + v], acc);
    }
    g3[((size_t)b * L_LEN + l) * 16 + v] = acc;
}

extern "C" void kernel_launch(void* const* d_in, const int* in_sizes, int n_in,
                              void* d_out, int out_size, void* d_ws, size_t ws_size,
                              hipStream_t stream) {
    const float* base = (const float*)d_in[0];
    const float* z    = (const float*)d_in[1];
    const float* cond = (const float*)d_in[2];
    const float* W1 = (const float*)d_in[4];  const float* b1 = (const float*)d_in[5];
    const float* W2 = (const float*)d_in[6];  const float* b2 = (const float*)d_in[7];
    const float* W3 = (const float*)d_in[8];  const float* b3 = (const float*)d_in[9];
    const float* W4 = (const float*)d_in[10]; const float* b4 = (const float*)d_in[11];
    const float* K1 = (const float*)d_in[12]; const float* cb1 = (const float*)d_in[13];
    const float* K2 = (const float*)d_in[14]; const float* cb2 = (const float*)d_in[15];
    const float* K3 = (const float*)d_in[16]; const float* cb3 = (const float*)d_in[17];
    float* out = (float*)d_out;

    int B = in_sizes[0] / T_LEN;   // 16
    const int CB = (T_LEN + 255) / 256;

    float* ws = (float*)d_ws;
    const size_t P1 = (size_t)16 * L_LEN * 128;    // per conv1 split
    const size_t P2 = (size_t)16 * L_LEN * 64;     // per conv2 split
    const size_t ZP = (size_t)16 * 10 * 128;       // zmean partials
    size_t need = (1024 + ZP + 4 * P1 + 2 * P2 + (size_t)16 * L_LEN * NV) * sizeof(float);

    float* P = ws;
    if (ws_size >= need) {
        float* zpart  = ws + 1024;
        float* parts1 = zpart + ZP;
        float* parts2 = parts1 + 4 * P1;
        float* g3     = parts2 + 2 * P2;
        zmean_kernel<<<B * 10, 256, 0, stream>>>(z, zpart);
        conv1_mlp_kernel<<<4 * B * 16 + B, 256, 0, stream>>>(
            z, cond, K1, parts1, zpart, W1, b1, W2, b2, W3, b3, W4, b4, P);
        conv2_split_kernel<<<2 * B * 16, 256, 0, stream>>>(parts1, cb1, K2, parts2);
        conv3_kernel<<<B * 16, 256, 0, stream>>>(parts2, cb2, K3, cb3, g3);
        main_kernel<<<B * CB, 256, 0, stream>>>(base, g3, P, out);
    } else {
        float* g1 = ws + 1024;
        float* g2 = g1 + (size_t)B * L_LEN * 128;
        float* g3 = g2 + (size_t)B * L_LEN * 64;
        params_kernel<<<B, 256, 0, stream>>>(z, cond, W1, b1, W2, b2, W3, b3, W4, b4, P);
        conv1_mono_kernel<<<B * 16, 256, 0, stream>>>(z, cond, K1, cb1, g1);
        conv2_mono_kernel<<<B * 16, 256, 0, stream>>>(g1, K2, cb2, g2);
        conv3_mono_kernel<<<B * 16, 256, 0, stream>>>(g2, K3, cb3, g3);
        main_kernel<<<B * CB, 256, 0, stream>>>(base, g3, P, out);
    }
}

// Round 4
// 65.276 us; speedup vs baseline: 2.2181x; 1.0343x over previous
//
#include <hip/hip_runtime.h>
#include <hip/hip_bf16.h>
#include <math.h>

#define L_LEN 250
#define D_DIM 128
#define C_DIM 32
#define DIN   160
#define NV    16
#define T_LEN 62400
#define CB    244            // ceil(62400/256)

// ------- kernel 1: blocks 0..15 = per-batch zmean+MLP ; 16..1039 = conv1 splitK
// P layout per batch (40 floats): [0]=depth, [1]=coef, [2..17]=mask, [18..33]=pan
__global__ __launch_bounds__(256) void conv1_mlp_kernel(
        const float* __restrict__ z, const float* __restrict__ cond,
        const float* __restrict__ K1, float* __restrict__ parts1,
        const float* __restrict__ W1, const float* __restrict__ b1,
        const float* __restrict__ W2, const float* __restrict__ b2,
        const float* __restrict__ W3, const float* __restrict__ b3,
        const float* __restrict__ W4, const float* __restrict__ b4,
        float* __restrict__ P) {
    int tid = threadIdx.x;
    if (blockIdx.x < 16) {
        // ---------------- MLP path (dispatched first, hides under conv1) ----
        int b = blockIdx.x;
        __shared__ float xb[DIN];
        __shared__ float4 sm4[8][32];
        __shared__ float h1[256];
        __shared__ float h2[128];
        __shared__ float h3[64];
        __shared__ float pr[4];
        {   // inline z-mean: 32 float4-cols x 8 row-groups, coalesced rows
            int c4 = tid & 31, rg = tid >> 5;
            const float4* zp = (const float4*)(z + (size_t)b * L_LEN * D_DIM) + c4;
            float4 acc = make_float4(0.f, 0.f, 0.f, 0.f);
            for (int r = rg; r < L_LEN; r += 8) {
                float4 v = zp[(size_t)r * 32];
                acc.x += v.x; acc.y += v.y; acc.z += v.z; acc.w += v.w;
            }
            sm4[rg][c4] = acc;
        }
        __syncthreads();
        if (tid < 32) {
            float4 acc = sm4[0][tid];
            #pragma unroll
            for (int g = 1; g < 8; ++g) {
                float4 v = sm4[g][tid];
                acc.x += v.x; acc.y += v.y; acc.z += v.z; acc.w += v.w;
            }
            const float inv = 1.0f / (float)L_LEN;
            acc.x *= inv; acc.y *= inv; acc.z *= inv; acc.w *= inv;
            ((float4*)xb)[tid] = acc;
        } else if (tid >= 128 && tid < DIN) {
            xb[tid] = cond[b * C_DIM + (tid - 128)];
        }
        __syncthreads();
        {
            float a0 = b1[tid], a1 = 0.f;
            #pragma unroll 8
            for (int i = 0; i < DIN; i += 2) {
                a0 = fmaf(xb[i],     W1[i * 256 + tid],       a0);
                a1 = fmaf(xb[i + 1], W1[(i + 1) * 256 + tid], a1);
            }
            h1[tid] = fmaxf(a0 + a1, 0.f);
        }
        __syncthreads();
        if (tid < 128) {
            float a0 = b2[tid], a1 = 0.f;
            #pragma unroll 8
            for (int i = 0; i < 256; i += 2) {
                a0 = fmaf(h1[i],     W2[i * 128 + tid],       a0);
                a1 = fmaf(h1[i + 1], W2[(i + 1) * 128 + tid], a1);
            }
            h2[tid] = fmaxf(a0 + a1, 0.f);
        }
        __syncthreads();
        if (tid < 64) {
            float a0 = b3[tid], a1 = 0.f;
            #pragma unroll 8
            for (int i = 0; i < 128; i += 2) {
                a0 = fmaf(h2[i],     W3[i * 64 + tid],       a0);
                a1 = fmaf(h2[i + 1], W3[(i + 1) * 64 + tid], a1);
            }
            h3[tid] = fmaxf(a0 + a1, 0.f);
        }
        __syncthreads();
        if (tid < 4) {
            float acc = b4[tid];
            #pragma unroll 8
            for (int i = 0; i < 64; ++i) acc = fmaf(h3[i], W4[i * 4 + tid], acc);
            pr[tid] = acc;
        }
        __syncthreads();
        if (tid == 0) {
            float num_voices = 1.0f + 14.0f / (1.0f + __expf(-pr[0]));
            float spread     = 1.0f / (1.0f + __expf(-pr[2]));
            float depth      = 0.5f / (1.0f + __expf(-pr[3]));
            float* Pb = P + b * 40;
            float msum = 0.f;
            for (int v = 0; v < NV; ++v) {
                float m = 1.0f / (1.0f + __expf(-(num_voices - (float)v) * 2.0f));
                msum += m;
                Pb[2 + v] = m;
                float pos = ((float)v - 7.5f) * (1.0f / 16.0f);
                Pb[2 + NV + v] = 1.0f - fabsf(pos) * spread * 0.5f;
            }
            float norm = sqrtf(msum + 1e-6f);
            Pb[0] = depth;
            Pb[1] = 1.0f / (norm + 1e-6f);
        }
        return;
    }
    // ---------------- conv1 split-K path ----------------
    int blk = blockIdx.x - 16;
    int s  = blk >> 8;           // ic split 0..3
    int b  = (blk >> 4) & 15;
    int lt = blk & 15;
    int l0 = lt * 16;
    __shared__ float smc[40][28];  // [ic_local][pl], p = l0-3+pl, 0..21
    for (int idx = tid; idx < 22 * 40; idx += 256) {
        int pl = idx / 40;
        int il = idx - pl * 40;
        int p  = l0 - 3 + pl;
        int gi = s * 40 + il;
        float v = 0.f;
        if (p >= 0 && p < L_LEN)
            v = (gi < D_DIM) ? z[((size_t)b * L_LEN + p) * D_DIM + gi]
                             : cond[b * C_DIM + (gi - D_DIM)];
        smc[il][pl] = v;
    }
    __syncthreads();
    int oc = tid & 127;
    int lb = (tid >> 7) * 8;
    float acc[8];
    #pragma unroll
    for (int j = 0; j < 8; ++j) acc[j] = 0.f;
    const float* kbase = K1 + (size_t)(s * 40) * 128 + oc;
    for (int il = 0; il < 40; ++il) {
        float zr[16];
        *(float4*)&zr[0]  = *(const float4*)&smc[il][lb];
        *(float4*)&zr[4]  = *(const float4*)&smc[il][lb + 4];
        *(float4*)&zr[8]  = *(const float4*)&smc[il][lb + 8];
        *(float4*)&zr[12] = *(const float4*)&smc[il][lb + 12];
        const float* kp = kbase + (size_t)il * 128;
        #pragma unroll
        for (int tap = 0; tap < 7; ++tap) {
            float k = kp[(size_t)tap * DIN * 128];
            #pragma unroll
            for (int j = 0; j < 8; ++j) acc[j] = fmaf(zr[tap + j], k, acc[j]);
        }
    }
    float* po = parts1 + (size_t)s * (16 * L_LEN * 128) + ((size_t)b * L_LEN) * 128 + oc;
    #pragma unroll
    for (int j = 0; j < 8; ++j) {
        int l = l0 + lb + j;
        if (l < L_LEN) po[(size_t)l * 128] = acc[j];
    }
}

// ---------------- conv2 split-K: grid = 2 * 16b * 16lt = 512 blocks ---------
__global__ __launch_bounds__(256) void conv2_split_kernel(
        const float* __restrict__ parts1, const float* __restrict__ cb1,
        const float* __restrict__ K2, float* __restrict__ parts2) {
    int blk = blockIdx.x;
    int h  = blk >> 8;           // ic split 0..1
    int b  = (blk >> 4) & 15;
    int lt = blk & 15;
    int l0 = lt * 16;
    int tid = threadIdx.x;
    const int PSTR = 16 * L_LEN * 128;
    __shared__ float sm[64][28];  // [ic_local][pl], p = l0-2+pl, 0..19
    for (int idx = tid; idx < 20 * 64; idx += 256) {
        int pl = idx >> 6;
        int il = idx & 63;
        int p  = l0 - 2 + pl;
        int gi = h * 64 + il;
        float v = 0.f;
        if (p >= 0 && p < L_LEN) {
            size_t o = ((size_t)b * L_LEN + p) * 128 + gi;
            v = cb1[gi] + parts1[o] + parts1[o + PSTR] + parts1[o + 2 * PSTR] + parts1[o + 3 * PSTR];
            v = fmaxf(v, 0.f);
        }
        sm[il][pl] = v;
    }
    __syncthreads();
    int oc = tid & 63;
    int lb = (tid >> 6) * 4;
    float acc[4];
    #pragma unroll
    for (int j = 0; j < 4; ++j) acc[j] = 0.f;
    const float* kbase = K2 + (size_t)(h * 64) * 64 + oc;
    for (int il = 0; il < 64; ++il) {
        float zr[8];
        *(float4*)&zr[0] = *(const float4*)&sm[il][lb];
        *(float4*)&zr[4] = *(const float4*)&sm[il][lb + 4];
        const float* kp = kbase + (size_t)il * 64;
        #pragma unroll
        for (int tap = 0; tap < 5; ++tap) {
            float k = kp[(size_t)tap * 128 * 64];
            #pragma unroll
            for (int j = 0; j < 4; ++j) acc[j] = fmaf(zr[tap + j], k, acc[j]);
        }
    }
    float* po = parts2 + (size_t)h * (16 * L_LEN * 64) + ((size_t)b * L_LEN) * 64 + oc;
    #pragma unroll
    for (int j = 0; j < 4; ++j) {
        int l = l0 + lb + j;
        if (l < L_LEN) po[(size_t)l * 64] = acc[j];
    }
}

// ------- kernel 3: fused conv3 + upsample + softplus + unison mix ----------
// grid = B*244. Each block computes the <=4 g3 rows its 256 t's interpolate.
__global__ __launch_bounds__(256) void conv3_main_kernel(
        const float* __restrict__ base, const float* __restrict__ parts2,
        const float* __restrict__ cb2,
        const float* __restrict__ K3, const float* __restrict__ cb3,
        const float* __restrict__ P, float* __restrict__ out) {
    int b = blockIdx.x / CB;
    int c = blockIdx.x % CB;
    int t0 = c * 256;
    int tid = threadIdx.x;
    const int PSTR2 = 16 * L_LEN * 64;
    const float scale = 250.0f / 62400.0f;

    __shared__ float k3t[16][196];   // [v][tap*64+ic]
    __shared__ float sA[6][68];      // g2 rows p = L0-1+pl (relu(cb2+sum parts2)), 0 if OOB
    __shared__ float g3loc[4][17];   // g3 rows L0..L0+3
    __shared__ float Pb[34];

    // block's base l-index (same fp formula as per-thread i0 below)
    float src0 = ((float)t0 + 0.5f) * scale - 0.5f;
    src0 = fminf(fmaxf(src0, 0.0f), 249.0f);
    int L0 = (int)floorf(src0);

    if (tid < 34) Pb[tid] = P[b * 40 + tid];
    for (int idx = tid; idx < 3 * 64 * 16; idx += 256) {
        int v  = idx & 15;
        int ti = idx >> 4;
        k3t[v][ti] = K3[ti * 16 + v];
    }
    for (int idx = tid; idx < 6 * 64; idx += 256) {
        int pl = idx >> 6;
        int i  = idx & 63;
        int p  = L0 - 1 + pl;
        float v = 0.f;
        if (p >= 0 && p < L_LEN) {
            size_t o = ((size_t)b * L_LEN + p) * 64 + i;
            v = fmaxf(cb2[i] + parts2[o] + parts2[o + PSTR2], 0.f);
        }
        sA[pl][i] = v;
    }
    __syncthreads();

    // conv3: 4 rows x 16 v x 4 ic-segments; quad shuffle-reduce
    {
        int seg = tid & 3;
        int v   = (tid >> 2) & 15;
        int r   = tid >> 6;          // g3 row = L0 + r (rows beyond valid range unread)
        float acc = 0.f;
        #pragma unroll
        for (int tap = 0; tap < 3; ++tap) {
            const float* gr = &sA[r + tap][seg * 16];
            const float* kr = &k3t[v][tap * 64 + seg * 16];
            #pragma unroll
            for (int j = 0; j < 4; ++j) {
                float4 g = *(const float4*)&gr[j * 4];
                float4 k = *(const float4*)&kr[j * 4];
                acc = fmaf(g.x, k.x, acc);
                acc = fmaf(g.y, k.y, acc);
                acc = fmaf(g.z, k.z, acc);
                acc = fmaf(g.w, k.w, acc);
            }
        }
        acc += __shfl_xor(acc, 1);
        acc += __shfl_xor(acc, 2);
        if (seg == 0) g3loc[r][v] = acc + cb3[v];
    }
    __syncthreads();

    int t = t0 + tid;
    if (t >= T_LEN) return;
    float depth = Pb[0];
    float coef  = Pb[1];
    float src = ((float)t + 0.5f) * scale - 0.5f;
    src = fminf(fmaxf(src, 0.0f), 249.0f);
    float fi0 = floorf(src);
    int i0 = (int)fi0;
    int i1 = min(i0 + 1, L_LEN - 1);
    float frac = src - fi0;
    int r0 = i0 - L0;
    int r1 = i1 - L0;
    float vg[16];
    #pragma unroll
    for (int v = 0; v < NV; ++v) {
        float a = g3loc[r0][v];
        float d = g3loc[r1][v];
        vg[v] = fmaf(d - a, frac, a);
    }
    float tsec = (float)t * (1.0f / 48000.0f);
    const float* bs = base + (size_t)b * T_LEN;
    const int shifts[NV] = {-9,-8,-6,-5,-4,-3,-1,0,0,1,3,4,5,6,8,9};
    float gain_sum = 0.f, uni = 0.f;
    #pragma unroll
    for (int v = 0; v < NV; ++v) {
        float x = vg[v];
        float sp = fmaxf(x, 0.f) + __logf(1.0f + __expf(-fabsf(x)));   // softplus
        float fv = 3.0f + 0.3f * (float)v;
        float ph = fv * tsec;
        ph -= floorf(ph);                       // revolutions in [0,1)
        float lfo = __builtin_amdgcn_sinf(ph);  // v_sin_f32: sin(2*pi*ph)
        int tb = t - shifts[v];
        if (tb < 0) tb += T_LEN; else if (tb >= T_LEN) tb -= T_LEN;
        float mod = bs[tb] * fmaf(0.2f * depth, lfo, 1.0f);
        gain_sum = fmaf(sp, Pb[2 + v], gain_sum);
        uni      = fmaf(mod * sp, Pb[2 + NV + v], uni);
    }
    out[(size_t)b * T_LEN + t] = gain_sum * coef * uni;
}

// ================= fallback (round-1 monolithic) kernels ====================
__global__ void params_kernel(const float* __restrict__ z, const float* __restrict__ cond,
                              const float* __restrict__ W1, const float* __restrict__ b1,
                              const float* __restrict__ W2, const float* __restrict__ b2,
                              const float* __restrict__ W3, const float* __restrict__ b3,
                              const float* __restrict__ W4, const float* __restrict__ b4,
                              float* __restrict__ P) {
    int b = blockIdx.x;
    int tid = threadIdx.x;
    __shared__ float xb[DIN];
    __shared__ float zp2[128];
    __shared__ float h1[256];
    __shared__ float h2[128];
    __shared__ float h3[64];
    __shared__ float pr[4];
    {
        int i = tid & 127, half = tid >> 7;
        const float* zp = z + (size_t)b * L_LEN * D_DIM + i;
        float s = 0.f;
        for (int l = half; l < L_LEN; l += 2) s += zp[(size_t)l * D_DIM];
        if (half) zp2[i] = s;
        __syncthreads();
        if (!half) xb[i] = (s + zp2[i]) * (1.0f / (float)L_LEN);
        if (tid >= 128 && tid < DIN) xb[tid] = cond[b * C_DIM + (tid - 128)];
    }
    __syncthreads();
    {
        float acc = b1[tid];
        for (int i = 0; i < DIN; ++i) acc = fmaf(xb[i], W1[i * 256 + tid], acc);
        h1[tid] = fmaxf(acc, 0.f);
    }
    __syncthreads();
    if (tid < 128) {
        float acc = b2[tid];
        for (int i = 0; i < 256; ++i) acc = fmaf(h1[i], W2[i * 128 + tid], acc);
        h2[tid] = fmaxf(acc, 0.f);
    }
    __syncthreads();
    if (tid < 64) {
        float acc = b3[tid];
        for (int i = 0; i < 128; ++i) acc = fmaf(h2[i], W3[i * 64 + tid], acc);
        h3[tid] = fmaxf(acc, 0.f);
    }
    __syncthreads();
    if (tid < 4) {
        float acc = b4[tid];
        for (int i = 0; i < 64; ++i) acc = fmaf(h3[i], W4[i * 4 + tid], acc);
        pr[tid] = acc;
    }
    __syncthreads();
    if (tid == 0) {
        float num_voices = 1.0f + 14.0f / (1.0f + __expf(-pr[0]));
        float spread     = 1.0f / (1.0f + __expf(-pr[2]));
        float depth      = 0.5f / (1.0f + __expf(-pr[3]));
        float* Pb = P + b * 40;
        float msum = 0.f;
        for (int v = 0; v < NV; ++v) {
            float m = 1.0f / (1.0f + __expf(-(num_voices - (float)v) * 2.0f));
            msum += m;
            Pb[2 + v] = m;
            float pos = ((float)v - 7.5f) * (1.0f / 16.0f);
            Pb[2 + NV + v] = 1.0f - fabsf(pos) * spread * 0.5f;
        }
        float norm = sqrtf(msum + 1e-6f);
        Pb[0] = depth;
        Pb[1] = 1.0f / (norm + 1e-6f);
    }
}

__global__ void conv1_mono_kernel(const float* __restrict__ z, const float* __restrict__ cond,
                                  const float* __restrict__ K1, const float* __restrict__ cb1,
                                  float* __restrict__ g1) {
    int b  = blockIdx.x >> 4;
    int lt = blockIdx.x & 15;
    int l0 = lt * 16;
    int tid = threadIdx.x;
    __shared__ float sm[DIN][22];
    for (int idx = tid; idx < 22 * DIN; idx += 256) {
        int pl = idx / DIN;
        int i  = idx - pl * DIN;
        int p  = l0 - 3 + pl;
        float v = 0.f;
        if (p >= 0 && p < L_LEN)
            v = (i < D_DIM) ? z[((size_t)b * L_LEN + p) * D_DIM + i]
                            : cond[b * C_DIM + (i - D_DIM)];
        sm[i][pl] = v;
    }
    __syncthreads();
    int oc = tid & 127;
    int lb = (tid >> 7) * 8;
    float bias = cb1[oc];
    float acc[8];
    #pragma unroll
    for (int j = 0; j < 8; ++j) acc[j] = bias;
    for (int i = 0; i < DIN; ++i) {
        float zr[14];
        #pragma unroll
        for (int q = 0; q < 14; ++q) zr[q] = sm[i][lb + q];
        #pragma unroll
        for (int tap = 0; tap < 7; ++tap) {
            float k = K1[(size_t)(tap * DIN + i) * 128 + oc];
            #pragma unroll
            for (int j = 0; j < 8; ++j) acc[j] = fmaf(zr[tap + j], k, acc[j]);
        }
    }
    #pragma unroll
    for (int j = 0; j < 8; ++j) {
        int l = l0 + lb + j;
        if (l < L_LEN) g1[((size_t)b * L_LEN + l) * 128 + oc] = fmaxf(acc[j], 0.f);
    }
}

__global__ void conv2_mono_kernel(const float* __restrict__ g1,
                                  const float* __restrict__ K2, const float* __restrict__ cb2,
                                  float* __restrict__ g2) {
    int b  = blockIdx.x >> 4;
    int lt = blockIdx.x & 15;
    int l0 = lt * 16;
    int tid = threadIdx.x;
    __shared__ float sm[128][20];
    for (int idx = tid; idx < 20 * 128; idx += 256) {
        int pl = idx >> 7;
        int i  = idx & 127;
        int p  = l0 - 2 + pl;
        float v = (p >= 0 && p < L_LEN) ? g1[((size_t)b * L_LEN + p) * 128 + i] : 0.f;
        sm[i][pl] = v;
    }
    __syncthreads();
    int oc = tid & 63;
    int lb = (tid >> 6) * 4;
    float bias = cb2[oc];
    float acc[4];
    #pragma unroll
    for (int j = 0; j < 4; ++j) acc[j] = bias;
    for (int i = 0; i < 128; ++i) {
        float zr[8];
        #pragma unroll
        for (int q = 0; q < 8; ++q) zr[q] = sm[i][lb + q];
        #pragma unroll
        for (int tap = 0; tap < 5; ++tap) {
            float k = K2[(size_t)(tap * 128 + i) * 64 + oc];
            #pragma unroll
            for (int j = 0; j < 4; ++j) acc[j] = fmaf(zr[tap + j], k, acc[j]);
        }
    }
    #pragma unroll
    for (int j = 0; j < 4; ++j) {
        int l = l0 + lb + j;
        if (l < L_LEN) g2[((size_t)b * L_LEN + l) * 64 + oc] = fmaxf(acc[j], 0.f);
    }
}

__global__ void conv3_mono_kernel(const float* __restrict__ g2,
                                  const float* __restrict__ K3, const float* __restrict__ cb3,
                                  float* __restrict__ g3) {
    int b  = blockIdx.x >> 4;
    int lt = blockIdx.x & 15;
    int l0 = lt * 16;
    int tid = threadIdx.x;
    int v  = tid & 15;
    int ll = tid >> 4;
    int l  = l0 + ll;
    if (l >= L_LEN) return;
    float acc = cb3[v];
    #pragma unroll
    for (int tap = 0; tap < 3; ++tap) {
        int p = l + tap - 1;
        if (p < 0 || p >= L_LEN) continue;
        const float* gp = g2 + ((size_t)b * L_LEN + p) * 64;
        #pragma unroll
        for (int i = 0; i < 64; ++i) acc = fmaf(gp[i], K3[(size_t)(tap * 64 + i) * 16 + v], acc);
    }
    g3[((size_t)b * L_LEN + l) * 16 + v] = acc;
}

__global__ __launch_bounds__(256) void main_mono_kernel(
        const float* __restrict__ base, const float* __restrict__ g3,
        const float* __restrict__ P, float* __restrict__ out) {
    int b = blockIdx.x / CB;
    int c = blockIdx.x % CB;
    int t = c * 256 + threadIdx.x;
    __shared__ float Pb[34];
    if (threadIdx.x < 34) Pb[threadIdx.x] = P[b * 40 + threadIdx.x];
    __syncthreads();
    if (t >= T_LEN) return;
    float depth = Pb[0];
    float coef  = Pb[1];
    const float scale = 250.0f / 62400.0f;
    float src = ((float)t + 0.5f) * scale - 0.5f;
    src = fminf(fmaxf(src, 0.0f), 249.0f);
    float fi0 = floorf(src);
    int i0 = (int)fi0;
    int i1 = min(i0 + 1, L_LEN - 1);
    float frac = src - fi0;
    const float4* r0 = (const float4*)(g3 + ((size_t)b * L_LEN + i0) * NV);
    const float4* r1 = (const float4*)(g3 + ((size_t)b * L_LEN + i1) * NV);
    float vg[16];
    #pragma unroll
    for (int q = 0; q < 4; ++q) {
        float4 a = r0[q];
        float4 d = r1[q];
        vg[q * 4 + 0] = fmaf(d.x - a.x, frac, a.x);
        vg[q * 4 + 1] = fmaf(d.y - a.y, frac, a.y);
        vg[q * 4 + 2] = fmaf(d.z - a.z, frac, a.z);
        vg[q * 4 + 3] = fmaf(d.w - a.w, frac, a.w);
    }
    float tsec = (float)t * (1.0f / 48000.0f);
    const float* bs = base + (size_t)b * T_LEN;
    const int shifts[NV] = {-9,-8,-6,-5,-4,-3,-1,0,0,1,3,4,5,6,8,9};
    float gain_sum = 0.f, uni = 0.f;
    #pragma unroll
    for (int v = 0; v < NV; ++v) {
        float x = vg[v];
        float sp = fmaxf(x, 0.f) + __logf(1.0f + __expf(-fabsf(x)));
        float fv = 3.0f + 0.3f * (float)v;
        float ph = fv * tsec;
        ph -= floorf(ph);
        float lfo = __builtin_amdgcn_sinf(ph);
        int tb = t - shifts[v];
        if (tb < 0) tb += T_LEN; else if (tb >= T_LEN) tb -= T_LEN;
        float mod = bs[tb] * fmaf(0.2f * depth, lfo, 1.0f);
        gain_sum = fmaf(sp, Pb[2 + v], gain_sum);
        uni      = fmaf(mod * sp, Pb[2 + NV + v], uni);
    }
    out[(size_t)b * T_LEN + t] = gain_sum * coef * uni;
}

extern "C" void kernel_launch(void* const* d_in, const int* in_sizes, int n_in,
                              void* d_out, int out_size, void* d_ws, size_t ws_size,
                              hipStream_t stream) {
    const float* base = (const float*)d_in[0];
    const float* z    = (const float*)d_in[1];
    const float* cond = (const float*)d_in[2];
    const float* W1 = (const float*)d_in[4];  const float* b1 = (const float*)d_in[5];
    const float* W2 = (const float*)d_in[6];  const float* b2 = (const float*)d_in[7];
    const float* W3 = (const float*)d_in[8];  const float* b3 = (const float*)d_in[9];
    const float* W4 = (const float*)d_in[10]; const float* b4 = (const float*)d_in[11];
    const float* K1 = (const float*)d_in[12]; const float* cb1 = (const float*)d_in[13];
    const float* K2 = (const float*)d_in[14]; const float* cb2 = (const float*)d_in[15];
    const float* K3 = (const float*)d_in[16]; const float* cb3 = (const float*)d_in[17];
    float* out = (float*)d_out;

    int B = in_sizes[0] / T_LEN;   // 16

    float* ws = (float*)d_ws;
    const size_t P1 = (size_t)16 * L_LEN * 128;    // per conv1 split
    const size_t P2 = (size_t)16 * L_LEN * 64;     // per conv2 split
    size_t need = (1024 + 4 * P1 + 2 * P2) * sizeof(float);

    float* P = ws;
    if (ws_size >= need) {
        float* parts1 = ws + 1024;
        float* parts2 = parts1 + 4 * P1;
        conv1_mlp_kernel<<<16 + 4 * B * 16, 256, 0, stream>>>(
            z, cond, K1, parts1, W1, b1, W2, b2, W3, b3, W4, b4, P);
        conv2_split_kernel<<<2 * B * 16, 256, 0, stream>>>(parts1, cb1, K2, parts2);
        conv3_main_kernel<<<B * CB, 256, 0, stream>>>(base, parts2, cb2, K3, cb3, P, out);
    } else {
        float* g1 = ws + 1024;
        float* g2 = g1 + (size_t)B * L_LEN * 128;
        float* g3 = g2 + (size_t)B * L_LEN * 64;
        params_kernel<<<B, 256, 0, stream>>>(z, cond, W1, b1, W2, b2, W3, b3, W4, b4, P);
        conv1_mono_kernel<<<B * 16, 256, 0, stream>>>(z, cond, K1, cb1, g1);
        conv2_mono_kernel<<<B * 16, 256, 0, stream>>>(g1, K2, cb2, g2);
        conv3_mono_kernel<<<B * 16, 256, 0, stream>>>(g2, K3, cb3, g3);
        main_mono_kernel<<<B * CB, 256, 0, stream>>>(base, g3, P, out);
    }
}